// Round 10
// baseline (217.165 us; speedup 1.0000x reference)
//
#include <hip/hip_runtime.h>
#include <hip/hip_bf16.h>
#include <math.h>

typedef _Float16 f16;
typedef __attribute__((ext_vector_type(8))) _Float16 f16x8;
typedef __attribute__((ext_vector_type(4))) _Float16 f16x4;
typedef __attribute__((ext_vector_type(2))) _Float16 f16x2;
typedef __attribute__((ext_vector_type(4))) float f32x4;

#define EMBED 1024
#define NHEADS 16
#define HDIM 64
#define BATCH 2
#define SEQ 2048
#define BS 4096  // BATCH*SEQ
#define LOG2E 1.4426950408889634f

// ---------------- ws layout (bytes) ----------------
// Xh:      0         (BS*EMBED f16 = 8388608)
// Wqkv_t:  8388608   (3072*1024 f16 = 6291456)
// Wout_t:  14680064  (1024*1024 f16 = 2097152)
// Qw:      16777216  [bh][s][d], pre-scaled by log2e
// Kp:      25165824  fragment-packed (permuted): [bh][kt32][c4][t2][lane64][8] f16
// Vp:      33554432  fragment-packed: [bh][kt32][cc2][dblk4][lane64][8] f16
// Ow:      41943040  ([B][S][H*64] f16)
// btab:    50331648  (16*4095 f32, pre-scaled by log2e)
//
// KEY PERMUTATION: within each 32-key chunk, S^T row m=quad*4+r of group g
// maps to key quad*8+g*4+r, so concat of two 16-key C-frags == K=32 A-frag
// for PV (8 mfma16x32 per 64-key tile). gemm_qkv writes Kp/Vp directly in
// this layout (no repack kernel).

__device__ __forceinline__ f32x4 mfma16x32(f16x8 a, f16x8 b, f32x4 c) {
  return __builtin_amdgcn_mfma_f32_16x16x32_f16(a, b, c, 0, 0, 0);
}
__device__ __forceinline__ f16x2 cvt_pk(float a, float b) {
  return __builtin_bit_cast(f16x2, __builtin_amdgcn_cvt_pkrtz(a, b));
}
__device__ __forceinline__ void gload_lds16(const f16* __restrict__ g, f16* l) {
  __builtin_amdgcn_global_load_lds(
      (const __attribute__((address_space(1))) void*)g,
      (__attribute__((address_space(3))) void*)l, 16, 0, 0);
}

// ------------- fused prep: cast X | transpose Wqkv | transpose Wout | bias table -------------
__global__ void prep_kernel(const float* __restrict__ X, const float* __restrict__ Wqkv,
                            const float* __restrict__ Wout, const float* __restrict__ rel_emb,
                            f16* __restrict__ Xh, f16* __restrict__ Wqkv_t,
                            f16* __restrict__ Wout_t, float* __restrict__ btab) {
  __shared__ float tile[32][33];
  int bid = blockIdx.x, tid = threadIdx.x;
  if (bid < 4096) {
    int i = (bid * 256 + tid) * 4;
    float4 v = *(const float4*)(X + i);
    f16x4 o = { (f16)v.x, (f16)v.y, (f16)v.z, (f16)v.w };
    *(f16x4*)(Xh + i) = o;
  } else if (bid < 8192) {
    const float* in;
    f16* out;
    int N, idx;
    if (bid < 7168) { in = Wqkv; out = Wqkv_t; N = 3072; idx = bid - 4096; }
    else            { in = Wout; out = Wout_t; N = 1024; idx = bid - 7168; }
    int nt = N / 32;
    int n0 = (idx % nt) * 32, k0 = (idx / nt) * 32;
    int tx = tid & 31, ty = tid >> 5;
#pragma unroll
    for (int r = ty; r < 32; r += 8) tile[r][tx] = in[(size_t)(k0 + r) * N + n0 + tx];
    __syncthreads();
#pragma unroll
    for (int r = ty; r < 32; r += 8) out[(size_t)(n0 + r) * 1024 + k0 + tx] = (f16)tile[tx][r];
  } else {
    int idx = (bid - 8192) * 256 + tid;  // 0..4094
    if (idx >= 4095) return;
    int rp = idx - 2047;
    int rb = rp > 0 ? 16 : 0;
    int arp = rp < 0 ? -rp : rp;
    int loc;
    if (arp < 8) {
      loc = arp;
    } else {
      float lr = logf((float)arp * 0.125f) * (1.0f / 2.7725887222397811f);
      int t = 8 + (int)(lr * 8.0f);
      loc = t < 15 ? t : 15;
    }
    int bucket = rb + loc;
#pragma unroll
    for (int h = 0; h < 16; h++) btab[h * 4095 + idx] = rel_emb[bucket * 16 + h] * LOG2E;
  }
}

// ------------- shared GEMM core (m97-style): C[128x128] = A[MxK] * Bt[NxK]^T -------------
__device__ __forceinline__ void gemm_core(const f16* __restrict__ A, const f16* __restrict__ Bt,
                                          int m0, int n0, int Kdim, f32x4 (&acc)[4][4]) {
  __shared__ __align__(16) f16 As[128 * 32];  // [m][k], 64 B rows, no pad
  __shared__ __align__(16) f16 Bs[128 * 32];  // [n][k]

  int tid = threadIdx.x;
  int lane = tid & 63, wave = tid >> 6;
  int l15 = lane & 15, quad = lane >> 4;
  int wr = (wave >> 1) * 64, wc = (wave & 1) * 64;
  int rowl = lane >> 2;          // 0..15: 4 lanes per 64-B row
  int col8 = (lane & 3) * 8;     // f16 offset of this lane's 16-B chunk

#pragma unroll
  for (int i = 0; i < 4; i++)
#pragma unroll
    for (int j = 0; j < 4; j++) acc[i][j] = f32x4{0.f, 0.f, 0.f, 0.f};

  for (int kt = 0; kt < Kdim / 32; kt++) {
    int kk = kt * 32;
#pragma unroll
    for (int c = 0; c < 2; c++) {
      int row = wave * 32 + c * 16 + rowl;
      gload_lds16(A + (size_t)(m0 + row) * Kdim + kk + col8, &As[(wave * 32 + c * 16) * 32]);
      gload_lds16(Bt + (size_t)(n0 + row) * Kdim + kk + col8, &Bs[(wave * 32 + c * 16) * 32]);
    }
    __syncthreads();
    f16x8 af[4], bf[4];
#pragma unroll
    for (int i = 0; i < 4; i++) af[i] = *(const f16x8*)(&As[(wr + i * 16 + l15) * 32 + quad * 8]);
#pragma unroll
    for (int j = 0; j < 4; j++) bf[j] = *(const f16x8*)(&Bs[(wc + j * 16 + l15) * 32 + quad * 8]);
#pragma unroll
    for (int i = 0; i < 4; i++)
#pragma unroll
      for (int j = 0; j < 4; j++) acc[i][j] = mfma16x32(af[i], bf[j], acc[i][j]);
    __syncthreads();
  }
}

// ------------- GEMM1: qkv = Xh @ Wqkv_t^T; Q (log2e-scaled), Kp+Vp fragment-direct -------------
__global__ __launch_bounds__(256, 3) void gemm_qkv_kernel(
    const f16* __restrict__ Xh, const f16* __restrict__ Wt,
    f16* __restrict__ Q, f16* __restrict__ Kp, f16* __restrict__ Vp) {
  f32x4 acc[4][4];
  int m0 = blockIdx.y * 128, n0 = blockIdx.x * 128;
  gemm_core(Xh, Wt, m0, n0, 1024, acc);

  int lane = threadIdx.x & 63, wave = threadIdx.x >> 6;
  int l15 = lane & 15, quad = lane >> 4;
  int wr = (wave >> 1) * 64, wc = (wave & 1) * 64;
  int nq = n0 + wc;          // 64-aligned; uniform per wave quadrant
  int which = nq >> 10;
  int h = (nq >> 6) & 15;
  int b = m0 >> 11;          // 128-tile never crosses batch boundary
  int kt = ((m0 & 2047) + wr) >> 6;

  if (which == 2) {
    // Vp[bh][kt][cc][dblk][lane][8] = V[key = cc*32 + quadr*8 + j-chunk][d = dblk*16 + ...]
    f16* vbase = Vp + (size_t)(b * 16 + h) * 131072 + (size_t)kt * 4096;
    int qr_lo = (quad >> 1);
    int joff = (quad & 1) * 4;
#pragma unroll
    for (int i = 0; i < 4; i++) {
      int cc = i >> 1;
      int qr = (i & 1) * 2 + qr_lo;
#pragma unroll
      for (int j = 0; j < 4; j++) {
        f16x4 pk = { (f16)acc[i][j][0], (f16)acc[i][j][1], (f16)acc[i][j][2], (f16)acc[i][j][3] };
        *(f16x4*)(vbase + (cc * 4 + j) * 512 + (qr * 16 + l15) * 8 + joff) = pk;
      }
    }
  } else if (which == 1) {
    // K direct to permuted fragment layout (verified vs old repack mapping):
    // slot = (cc*2+g)*2 + t; lane_k = quadk*16 + l15k; jj = l15&7
    // cc=i>>1, g=quad&1, t=j>>1, quadk=(j&1)*2+(l15>>3), l15k=((i&1)*2+(quad>>1))*4+r
    f16* kbase = Kp + (size_t)(b * 16 + h) * 131072 + (size_t)kt * 4096;
    int jj = l15 & 7;
    int qk_half = l15 >> 3;
    int g = quad & 1;
    int hi2 = quad >> 1;
#pragma unroll
    for (int i = 0; i < 4; i++) {
      int cc = i >> 1;
      int m_hi = ((i & 1) * 2 + hi2) * 4;
#pragma unroll
      for (int j = 0; j < 4; j++) {
        int slot = (cc * 2 + g) * 2 + (j >> 1);
        int quadk = (j & 1) * 2 + qk_half;
#pragma unroll
        for (int r = 0; r < 4; r++) {
          kbase[slot * 512 + (quadk * 16 + m_hi + r) * 8 + jj] = (f16)acc[i][j][r];
        }
      }
    }
  } else {
    // Q: [bh][s][d], scaled by log2e
#pragma unroll
    for (int i = 0; i < 4; i++) {
#pragma unroll
      for (int j = 0; j < 4; j++) {
        int d = j * 16 + l15;
#pragma unroll
        for (int r = 0; r < 4; r++) {
          int m = m0 + wr + i * 16 + quad * 4 + r;
          int s = m & 2047;
          Q[(((size_t)(b * 16 + h) * 2048 + s) << 6) + d] = (f16)(acc[i][j][r] * LOG2E);
        }
      }
    }
  }
}

// ------------- flash attention: K register-double-buffered, bias add-after-MFMA -------------
__global__ __launch_bounds__(256, 4) void attn_kernel(
    const f16* __restrict__ Q, const f16* __restrict__ Kp, const f16* __restrict__ Vp,
    const float* __restrict__ btab, f16* __restrict__ O) {
  __shared__ float bias_lds[2112];   // scalar reads: conflict-free by construction

  int qt = blockIdx.x, bh = blockIdx.y;
  int qbase = qt * 64;
  int h = bh & 15, b = bh >> 4;
  int tid = threadIdx.x, lane = tid & 63, wave = tid >> 6;
  int l15 = lane & 15, quad = lane >> 4;

  const float* brow = btab + h * 4095 + (1984 - qbase);
  for (int i = tid; i < 2111; i += 256) bias_lds[i] = brow[i];

  // Q fragments (B-operand of S^T mfma): B[n=q(l15)][k=d]
  const f16* qptr = Q + ((size_t)bh * 2048 + qbase + wave * 16 + l15) * 64 + quad * 8;
  f16x8 qf0 = *(const f16x8*)(qptr);
  f16x8 qf1 = *(const f16x8*)(qptr + 32);

  f32x4 accO[4] = {};                // O[q=quad*4+r][d=dblk*16+l15]
  float m_i = -INFINITY;             // per-lane running max for q = l15 (log2 space)
  float l_acc = 0.f;                 // per-lane partial sum

  const f16* kbase = Kp + (size_t)bh * 131072 + 1792;  // centered: slot offs in +-3584 B
  const f16* vbase = Vp + (size_t)bh * 131072 + 1792;
  const int voff = lane * 8;
  const int bofs = quad * 8 - wave * 16 - l15 + 63;

  __syncthreads();

  // one tile's worth of processing; kf pre-loaded, V loaded inside (softmax-hidden)
  auto do_tile = [&](const f16x8 (&kf)[8], const f16* vc, const float* bb) {
    // QK: S^T C-frags, zero-init (bias added after so LDS latency is off the path)
    f32x4 scT[4] = {};
#pragma unroll
    for (int c = 0; c < 4; c++) {
      scT[c] = mfma16x32(kf[c * 2 + 0], qf0, scT[c]);
      scT[c] = mfma16x32(kf[c * 2 + 1], qf1, scT[c]);
    }
    // V fragments: issued now, consumed after softmax
    f16x8 vf[2][4];
#pragma unroll
    for (int cc = 0; cc < 2; cc++)
#pragma unroll
      for (int dblk = 0; dblk < 4; dblk++)
        vf[cc][dblk] = *(const f16x8*)(vc + ((cc * 4 + dblk) * 512 - 1792) + voff);
    // bias add (c -> offset (c>>1)*32 + (c&1)*4)
    scT[0] += f32x4{ bb[0],  bb[1],  bb[2],  bb[3]  };
    scT[1] += f32x4{ bb[4],  bb[5],  bb[6],  bb[7]  };
    scT[2] += f32x4{ bb[32], bb[33], bb[34], bb[35] };
    scT[3] += f32x4{ bb[36], bb[37], bb[38], bb[39] };
    // per-lane partial max
    float mp0 = fmaxf(fmaxf(fmaxf(scT[0][0], scT[0][1]), scT[0][2]), scT[0][3]);
    float mp1 = fmaxf(fmaxf(fmaxf(scT[1][0], scT[1][1]), scT[1][2]), scT[1][3]);
    float mp2 = fmaxf(fmaxf(fmaxf(scT[2][0], scT[2][1]), scT[2][2]), scT[2][3]);
    float mp3 = fmaxf(fmaxf(fmaxf(scT[3][0], scT[3][1]), scT[3][2]), scT[3][3]);
    float mp = fmaxf(fmaxf(fmaxf(mp0, mp1), mp2), mp3);
    if (__any(mp > m_i)) {
      float mx = fmaxf(mp, __shfl_xor(mp, 16));
      mx = fmaxf(mx, __shfl_xor(mx, 32));
      float mn = fmaxf(m_i, mx);
      float alpha = __builtin_amdgcn_exp2f(m_i - mn);
      m_i = mn;
      l_acc *= alpha;
      float arow[4];
#pragma unroll
      for (int r = 0; r < 4; r++) arow[r] = __shfl(alpha, quad * 4 + r);
#pragma unroll
      for (int d = 0; d < 4; d++)
#pragma unroll
        for (int r = 0; r < 4; r++) accO[d][r] *= arow[r];
    }
    float mx = m_i;
    f16x4 p[4];
#pragma unroll
    for (int c = 0; c < 4; c++) {
      float e0 = __builtin_amdgcn_exp2f(scT[c][0] - mx);
      float e1 = __builtin_amdgcn_exp2f(scT[c][1] - mx);
      float e2 = __builtin_amdgcn_exp2f(scT[c][2] - mx);
      float e3 = __builtin_amdgcn_exp2f(scT[c][3] - mx);
      l_acc += (e0 + e1) + (e2 + e3);
      f16x2 plo = cvt_pk(e0, e1);
      f16x2 phi = cvt_pk(e2, e3);
      p[c][0] = plo[0]; p[c][1] = plo[1]; p[c][2] = phi[0]; p[c][3] = phi[1];
    }
    f16x8 pp0 = __builtin_shufflevector(p[0], p[1], 0, 1, 2, 3, 4, 5, 6, 7);
    f16x8 pp1 = __builtin_shufflevector(p[2], p[3], 0, 1, 2, 3, 4, 5, 6, 7);
#pragma unroll
    for (int dblk = 0; dblk < 4; dblk++) accO[dblk] = mfma16x32(pp0, vf[0][dblk], accO[dblk]);
#pragma unroll
    for (int dblk = 0; dblk < 4; dblk++) accO[dblk] = mfma16x32(pp1, vf[1][dblk], accO[dblk]);
  };

  // K register double-buffer, unroll 2
  f16x8 k0[8], k1[8];
#pragma unroll
  for (int u = 0; u < 8; u++) k0[u] = *(const f16x8*)(kbase + (u * 512 - 1792) + voff);

  for (int ktp = 0; ktp < 16; ktp++) {
    int ktA = 2 * ktp, ktB = 2 * ktp + 1;
    // prefetch K(ktB) into k1 (hidden by tile A's work)
    const f16* kB = kbase + (size_t)ktB * 4096;
#pragma unroll
    for (int u = 0; u < 8; u++) k1[u] = *(const f16x8*)(kB + (u * 512 - 1792) + voff);
    do_tile(k0, vbase + (size_t)ktA * 4096, &bias_lds[ktA * 64 + bofs]);
    // prefetch K(ktB+1) into k0 (clamped on last)
    const f16* kC = kbase + (size_t)(ktB < 31 ? ktB + 1 : ktB) * 4096;
#pragma unroll
    for (int u = 0; u < 8; u++) k0[u] = *(const f16x8*)(kC + (u * 512 - 1792) + voff);
    do_tile(k1, vbase + (size_t)ktB * 4096, &bias_lds[ktB * 64 + bofs]);
  }

  // epilogue: reduce l across quads, then O[q][d] / l -> Ow[b][s][h*64+d]
  float lt = l_acc;
  lt += __shfl_xor(lt, 16);
  lt += __shfl_xor(lt, 32);
  float linv = __builtin_amdgcn_rcpf(lt);
  float lrow[4];
#pragma unroll
  for (int r = 0; r < 4; r++) lrow[r] = __shfl(linv, quad * 4 + r);
#pragma unroll
  for (int dblk = 0; dblk < 4; dblk++) {
#pragma unroll
    for (int r = 0; r < 4; r++) {
      int q = qbase + wave * 16 + quad * 4 + r;
      O[((size_t)(b * 2048 + q) << 10) + h * 64 + dblk * 16 + l15] = (f16)(accO[dblk][r] * lrow[r]);
    }
  }
}

// ------------- GEMM2: out = Ow @ Wout_t^T (fp32 out), 128(M)x64(N) tiles -------------
__global__ __launch_bounds__(256, 2) void gemm_out_kernel(
    const f16* __restrict__ Oh, const f16* __restrict__ Wt, float* __restrict__ out) {
  __shared__ __align__(16) f16 As[128 * 32];  // [m][k]
  __shared__ __align__(16) f16 Bs[64 * 32];   // [n][k]

  int tid = threadIdx.x;
  int lane = tid & 63, wave = tid >> 6;
  int l15 = lane & 15, quad = lane >> 4;
  int rowl = lane >> 2;
  int col8 = (lane & 3) * 8;
  int m0 = blockIdx.y * 128, n0 = blockIdx.x * 64;
  int wr = wave * 32;

  f32x4 acc[2][4];
#pragma unroll
  for (int i = 0; i < 2; i++)
#pragma unroll
    for (int j = 0; j < 4; j++) acc[i][j] = f32x4{0.f, 0.f, 0.f, 0.f};

  for (int kt = 0; kt < 32; kt++) {
    int kk = kt * 32;
#pragma unroll
    for (int c = 0; c < 2; c++) {
      int row = wave * 32 + c * 16 + rowl;
      gload_lds16(Oh + (size_t)(m0 + row) * 1024 + kk + col8, &As[(wave * 32 + c * 16) * 32]);
    }
    {
      int row = wave * 16 + rowl;
      gload_lds16(Wt + (size_t)(n0 + row) * 1024 + kk + col8, &Bs[(wave * 16) * 32]);
    }
    __syncthreads();
    f16x8 af[2], bf[4];
#pragma unroll
    for (int i = 0; i < 2; i++) af[i] = *(const f16x8*)(&As[(wr + i * 16 + l15) * 32 + quad * 8]);
#pragma unroll
    for (int j = 0; j < 4; j++) bf[j] = *(const f16x8*)(&Bs[(j * 16 + l15) * 32 + quad * 8]);
#pragma unroll
    for (int i = 0; i < 2; i++)
#pragma unroll
      for (int j = 0; j < 4; j++) acc[i][j] = mfma16x32(af[i], bf[j], acc[i][j]);
    __syncthreads();
  }

#pragma unroll
  for (int i = 0; i < 2; i++) {
#pragma unroll
    for (int j = 0; j < 4; j++) {
      int n = n0 + j * 16 + l15;
#pragma unroll
      for (int r = 0; r < 4; r++) {
        int m = m0 + wr + i * 16 + quad * 4 + r;
        out[((size_t)m << 10) + n] = acc[i][j][r];
      }
    }
  }
}

extern "C" void kernel_launch(void* const* d_in, const int* in_sizes, int n_in,
                              void* d_out, int out_size, void* d_ws, size_t ws_size,
                              hipStream_t stream) {
  const float* X = (const float*)d_in[0];     // (2,2048,1024)
  const float* Wqkv = (const float*)d_in[1];  // (1024,3072)
  const float* Wout = (const float*)d_in[2];  // (1024,1024)
  const float* rel = (const float*)d_in[3];   // (32,16)

  char* ws = (char*)d_ws;
  f16* Xh     = (f16*)(ws + 0);
  f16* Wqkv_t = (f16*)(ws + 8388608);
  f16* Wout_t = (f16*)(ws + 14680064);
  f16* Qw     = (f16*)(ws + 16777216);
  f16* Kp     = (f16*)(ws + 25165824);
  f16* Vp     = (f16*)(ws + 33554432);
  f16* Ow     = (f16*)(ws + 41943040);
  float* btab = (float*)(ws + 50331648);

  prep_kernel<<<8208, 256, 0, stream>>>(X, Wqkv, Wout, rel, Xh, Wqkv_t, Wout_t, btab);
  gemm_qkv_kernel<<<dim3(24, 32), 256, 0, stream>>>(Xh, Wqkv_t, Qw, Kp, Vp);
  attn_kernel<<<dim3(32, 32), 256, 0, stream>>>(Qw, Kp, Vp, btab, Ow);
  gemm_out_kernel<<<dim3(16, 32), 256, 0, stream>>>(Ow, Wout_t, (float*)d_out);
}

// Round 12
// 204.905 us; speedup vs baseline: 1.0598x; 1.0598x over previous
//
#include <hip/hip_runtime.h>
#include <hip/hip_bf16.h>
#include <math.h>

typedef _Float16 f16;
typedef __attribute__((ext_vector_type(8))) _Float16 f16x8;
typedef __attribute__((ext_vector_type(4))) _Float16 f16x4;
typedef __attribute__((ext_vector_type(2))) _Float16 f16x2;
typedef __attribute__((ext_vector_type(4))) float f32x4;

#define EMBED 1024
#define NHEADS 16
#define HDIM 64
#define BATCH 2
#define SEQ 2048
#define BS 4096  // BATCH*SEQ
#define LOG2E 1.4426950408889634f
#define NEG_BIG -3.0e38f

// ---------------- ws layout (bytes) ----------------
// Xh:      0         (BS*EMBED f16 = 8388608)
// Wqkv_t:  8388608   (3072*1024 f16 = 6291456)
// Wout_t:  14680064  (1024*1024 f16 = 2097152)
// Qw:      16777216  [bh][s][d], pre-scaled by log2e
// Kp:      25165824  fragment-packed (permuted): [bh][kt32][c4][t2][lane64][8] f16
// Vp:      33554432  fragment-packed: [bh][kt32][cc2][dblk4][lane64][8] f16
// Ow:      41943040  ([B][S][H*64] f16)
// btab:    50331648  (16*4095 f32, pre-scaled by log2e)
//
// ATTN: each wave handles ALL 4 q-groups (64 q) for its 1/4 of key-tiles
// (kt = wave + 4t); K/V regs reused across q-groups (4x less VMEM). Per-wave
// softmax states merged flash-decoding-style in the epilogue. l_acc is
// quad-reduced BEFORE the merge store (round-11 bug). Finite -3e38 sentinel
// instead of -inf (no inf arithmetic anywhere).

__device__ __forceinline__ f32x4 mfma16x32(f16x8 a, f16x8 b, f32x4 c) {
  return __builtin_amdgcn_mfma_f32_16x16x32_f16(a, b, c, 0, 0, 0);
}
__device__ __forceinline__ f16x2 cvt_pk(float a, float b) {
  return __builtin_bit_cast(f16x2, __builtin_amdgcn_cvt_pkrtz(a, b));
}
__device__ __forceinline__ void gload_lds16(const f16* __restrict__ g, f16* l) {
  __builtin_amdgcn_global_load_lds(
      (const __attribute__((address_space(1))) void*)g,
      (__attribute__((address_space(3))) void*)l, 16, 0, 0);
}

// ------------- fused prep: cast X | transpose Wqkv | transpose Wout | bias table -------------
__global__ void prep_kernel(const float* __restrict__ X, const float* __restrict__ Wqkv,
                            const float* __restrict__ Wout, const float* __restrict__ rel_emb,
                            f16* __restrict__ Xh, f16* __restrict__ Wqkv_t,
                            f16* __restrict__ Wout_t, float* __restrict__ btab) {
  __shared__ float tile[32][33];
  int bid = blockIdx.x, tid = threadIdx.x;
  if (bid < 4096) {
    int i = (bid * 256 + tid) * 4;
    float4 v = *(const float4*)(X + i);
    f16x4 o = { (f16)v.x, (f16)v.y, (f16)v.z, (f16)v.w };
    *(f16x4*)(Xh + i) = o;
  } else if (bid < 8192) {
    const float* in;
    f16* out;
    int N, idx;
    if (bid < 7168) { in = Wqkv; out = Wqkv_t; N = 3072; idx = bid - 4096; }
    else            { in = Wout; out = Wout_t; N = 1024; idx = bid - 7168; }
    int nt = N / 32;
    int n0 = (idx % nt) * 32, k0 = (idx / nt) * 32;
    int tx = tid & 31, ty = tid >> 5;
#pragma unroll
    for (int r = ty; r < 32; r += 8) tile[r][tx] = in[(size_t)(k0 + r) * N + n0 + tx];
    __syncthreads();
#pragma unroll
    for (int r = ty; r < 32; r += 8) out[(size_t)(n0 + r) * 1024 + k0 + tx] = (f16)tile[tx][r];
  } else {
    int idx = (bid - 8192) * 256 + tid;  // 0..4094
    if (idx >= 4095) return;
    int rp = idx - 2047;
    int rb = rp > 0 ? 16 : 0;
    int arp = rp < 0 ? -rp : rp;
    int loc;
    if (arp < 8) {
      loc = arp;
    } else {
      float lr = logf((float)arp * 0.125f) * (1.0f / 2.7725887222397811f);
      int t = 8 + (int)(lr * 8.0f);
      loc = t < 15 ? t : 15;
    }
    int bucket = rb + loc;
#pragma unroll
    for (int h = 0; h < 16; h++) btab[h * 4095 + idx] = rel_emb[bucket * 16 + h] * LOG2E;
  }
}

// ------------- shared GEMM core (m97-style): C[128x128] = A[MxK] * Bt[NxK]^T -------------
__device__ __forceinline__ void gemm_core(const f16* __restrict__ A, const f16* __restrict__ Bt,
                                          int m0, int n0, int Kdim, f32x4 (&acc)[4][4]) {
  __shared__ __align__(16) f16 As[128 * 32];  // [m][k], 64 B rows, no pad
  __shared__ __align__(16) f16 Bs[128 * 32];  // [n][k]

  int tid = threadIdx.x;
  int lane = tid & 63, wave = tid >> 6;
  int l15 = lane & 15, quad = lane >> 4;
  int wr = (wave >> 1) * 64, wc = (wave & 1) * 64;
  int rowl = lane >> 2;          // 0..15: 4 lanes per 64-B row
  int col8 = (lane & 3) * 8;     // f16 offset of this lane's 16-B chunk

#pragma unroll
  for (int i = 0; i < 4; i++)
#pragma unroll
    for (int j = 0; j < 4; j++) acc[i][j] = f32x4{0.f, 0.f, 0.f, 0.f};

  for (int kt = 0; kt < Kdim / 32; kt++) {
    int kk = kt * 32;
#pragma unroll
    for (int c = 0; c < 2; c++) {
      int row = wave * 32 + c * 16 + rowl;
      gload_lds16(A + (size_t)(m0 + row) * Kdim + kk + col8, &As[(wave * 32 + c * 16) * 32]);
      gload_lds16(Bt + (size_t)(n0 + row) * Kdim + kk + col8, &Bs[(wave * 32 + c * 16) * 32]);
    }
    __syncthreads();
    f16x8 af[4], bf[4];
#pragma unroll
    for (int i = 0; i < 4; i++) af[i] = *(const f16x8*)(&As[(wr + i * 16 + l15) * 32 + quad * 8]);
#pragma unroll
    for (int j = 0; j < 4; j++) bf[j] = *(const f16x8*)(&Bs[(wc + j * 16 + l15) * 32 + quad * 8]);
#pragma unroll
    for (int i = 0; i < 4; i++)
#pragma unroll
      for (int j = 0; j < 4; j++) acc[i][j] = mfma16x32(af[i], bf[j], acc[i][j]);
    __syncthreads();
  }
}

// ------------- GEMM1: qkv = Xh @ Wqkv_t^T; Q (log2e-scaled), Kp+Vp fragment-direct -------------
__global__ __launch_bounds__(256, 3) void gemm_qkv_kernel(
    const f16* __restrict__ Xh, const f16* __restrict__ Wt,
    f16* __restrict__ Q, f16* __restrict__ Kp, f16* __restrict__ Vp) {
  f32x4 acc[4][4];
  int m0 = blockIdx.y * 128, n0 = blockIdx.x * 128;
  gemm_core(Xh, Wt, m0, n0, 1024, acc);

  int lane = threadIdx.x & 63, wave = threadIdx.x >> 6;
  int l15 = lane & 15, quad = lane >> 4;
  int wr = (wave >> 1) * 64, wc = (wave & 1) * 64;
  int nq = n0 + wc;          // 64-aligned; uniform per wave quadrant
  int which = nq >> 10;
  int h = (nq >> 6) & 15;
  int b = m0 >> 11;          // 128-tile never crosses batch boundary
  int kt = ((m0 & 2047) + wr) >> 6;

  if (which == 2) {
    // Vp[bh][kt][cc][dblk][lane][8]
    f16* vbase = Vp + (size_t)(b * 16 + h) * 131072 + (size_t)kt * 4096;
    int qr_lo = (quad >> 1);
    int joff = (quad & 1) * 4;
#pragma unroll
    for (int i = 0; i < 4; i++) {
      int cc = i >> 1;
      int qr = (i & 1) * 2 + qr_lo;
#pragma unroll
      for (int j = 0; j < 4; j++) {
        f16x4 pk = { (f16)acc[i][j][0], (f16)acc[i][j][1], (f16)acc[i][j][2], (f16)acc[i][j][3] };
        *(f16x4*)(vbase + (cc * 4 + j) * 512 + (qr * 16 + l15) * 8 + joff) = pk;
      }
    }
  } else if (which == 1) {
    // K direct to permuted fragment layout
    f16* kbase = Kp + (size_t)(b * 16 + h) * 131072 + (size_t)kt * 4096;
    int jj = l15 & 7;
    int qk_half = l15 >> 3;
    int g = quad & 1;
    int hi2 = quad >> 1;
#pragma unroll
    for (int i = 0; i < 4; i++) {
      int cc = i >> 1;
      int m_hi = ((i & 1) * 2 + hi2) * 4;
#pragma unroll
      for (int j = 0; j < 4; j++) {
        int slot = (cc * 2 + g) * 2 + (j >> 1);
        int quadk = (j & 1) * 2 + qk_half;
#pragma unroll
        for (int r = 0; r < 4; r++) {
          kbase[slot * 512 + (quadk * 16 + m_hi + r) * 8 + jj] = (f16)acc[i][j][r];
        }
      }
    }
  } else {
    // Q: [bh][s][d], scaled by log2e
#pragma unroll
    for (int i = 0; i < 4; i++) {
#pragma unroll
      for (int j = 0; j < 4; j++) {
        int d = j * 16 + l15;
#pragma unroll
        for (int r = 0; r < 4; r++) {
          int m = m0 + wr + i * 16 + quad * 4 + r;
          int s = m & 2047;
          Q[(((size_t)(b * 16 + h) * 2048 + s) << 6) + d] = (f16)(acc[i][j][r] * LOG2E);
        }
      }
    }
  }
}

// ------------- flash attention: wave = 1/4 of key tiles x ALL 64 q -------------
__global__ __launch_bounds__(256, 2) void attn_kernel(
    const f16* __restrict__ Q, const f16* __restrict__ Kp, const f16* __restrict__ Vp,
    const float* __restrict__ btab, f16* __restrict__ O) {
  __shared__ float sbuf[2112];       // bias only (read-only after init)
  __shared__ float obuf[4096];       // cross-wave O accumulation (separate!)
  __shared__ float mred[4][4][16];   // [g][wave][l15]
  __shared__ float lred[4][4][16];

  // XCD swizzle: 4 bh per XCD -> K/V stays L2-resident per XCD
  int blk = blockIdx.x;
  int bh = (blk & 7) * 4 + ((blk >> 3) & 3);
  int qt = blk >> 5;
  int qbase = qt * 64;
  int h = bh & 15, b = bh >> 4;
  int tid = threadIdx.x, lane = tid & 63, wave = tid >> 6;
  int l15 = lane & 15, quad = lane >> 4;

  const float* brow = btab + h * 4095 + (1984 - qbase);
  for (int i = tid; i < 2111; i += 256) sbuf[i] = brow[i];

  // Q fragments for ALL 4 q-groups (B-operand of S^T mfma): q = qbase + g*16 + l15
  f16x8 qf[4][2];
#pragma unroll
  for (int g = 0; g < 4; g++) {
    const f16* qptr = Q + ((size_t)bh * 2048 + qbase + g * 16 + l15) * 64 + quad * 8;
    qf[g][0] = *(const f16x8*)(qptr);
    qf[g][1] = *(const f16x8*)(qptr + 32);
  }

  f32x4 accO[4][4] = {};             // [g][dblk]: O[q=g*16+quad*4+r][d=dblk*16+l15]
  float m_i[4], l_acc[4];            // per-lane per-group state, q = g*16 + l15
#pragma unroll
  for (int g = 0; g < 4; g++) { m_i[g] = NEG_BIG; l_acc[g] = 0.f; }

  const f16* kbase = Kp + (size_t)bh * 131072 + 1792;  // centered: offs in +-3584 B
  const f16* vbase = Vp + (size_t)bh * 131072 + 1792;
  const int voff = lane * 8;

  __syncthreads();

  for (int t = 0; t < 8; t++) {
    int kt = t * 4 + wave;           // this wave's tile subset
    const f16* kc = kbase + (size_t)kt * 4096;
    const f16* vc = vbase + (size_t)kt * 4096;
    f16x8 kf[8], vf[8];
#pragma unroll
    for (int u = 0; u < 8; u++) kf[u] = *(const f16x8*)(kc + (u * 512 - 1792) + voff);
#pragma unroll
    for (int u = 0; u < 8; u++) vf[u] = *(const f16x8*)(vc + (u * 512 - 1792) + voff);
    const float* btile = &sbuf[kt * 64 + quad * 8 - l15 + 63];

#pragma unroll
    for (int g = 0; g < 4; g++) {
      const float* bb = btile - g * 16;
      f32x4 scT[4] = {};
#pragma unroll
      for (int c = 0; c < 4; c++) {
        scT[c] = mfma16x32(kf[c * 2 + 0], qf[g][0], scT[c]);
        scT[c] = mfma16x32(kf[c * 2 + 1], qf[g][1], scT[c]);
      }
      scT[0] += f32x4{ bb[0],  bb[1],  bb[2],  bb[3]  };
      scT[1] += f32x4{ bb[4],  bb[5],  bb[6],  bb[7]  };
      scT[2] += f32x4{ bb[32], bb[33], bb[34], bb[35] };
      scT[3] += f32x4{ bb[36], bb[37], bb[38], bb[39] };
      float mp0 = fmaxf(fmaxf(fmaxf(scT[0][0], scT[0][1]), scT[0][2]), scT[0][3]);
      float mp1 = fmaxf(fmaxf(fmaxf(scT[1][0], scT[1][1]), scT[1][2]), scT[1][3]);
      float mp2 = fmaxf(fmaxf(fmaxf(scT[2][0], scT[2][1]), scT[2][2]), scT[2][3]);
      float mp3 = fmaxf(fmaxf(fmaxf(scT[3][0], scT[3][1]), scT[3][2]), scT[3][3]);
      float mp = fmaxf(fmaxf(fmaxf(mp0, mp1), mp2), mp3);
      if (__any(mp > m_i[g])) {
        float mx = fmaxf(mp, __shfl_xor(mp, 16));
        mx = fmaxf(mx, __shfl_xor(mx, 32));
        float mn = fmaxf(m_i[g], mx);
        float alpha = __builtin_amdgcn_exp2f(m_i[g] - mn);
        m_i[g] = mn;
        l_acc[g] *= alpha;
        float arow[4];
#pragma unroll
        for (int r = 0; r < 4; r++) arow[r] = __shfl(alpha, quad * 4 + r);
#pragma unroll
        for (int d = 0; d < 4; d++)
#pragma unroll
          for (int r = 0; r < 4; r++) accO[g][d][r] *= arow[r];
      }
      float mx = m_i[g];
      f16x4 p[4];
#pragma unroll
      for (int c = 0; c < 4; c++) {
        float e0 = __builtin_amdgcn_exp2f(scT[c][0] - mx);
        float e1 = __builtin_amdgcn_exp2f(scT[c][1] - mx);
        float e2 = __builtin_amdgcn_exp2f(scT[c][2] - mx);
        float e3 = __builtin_amdgcn_exp2f(scT[c][3] - mx);
        l_acc[g] += (e0 + e1) + (e2 + e3);
        f16x2 plo = cvt_pk(e0, e1);
        f16x2 phi = cvt_pk(e2, e3);
        p[c][0] = plo[0]; p[c][1] = plo[1]; p[c][2] = phi[0]; p[c][3] = phi[1];
      }
      f16x8 pp0 = __builtin_shufflevector(p[0], p[1], 0, 1, 2, 3, 4, 5, 6, 7);
      f16x8 pp1 = __builtin_shufflevector(p[2], p[3], 0, 1, 2, 3, 4, 5, 6, 7);
#pragma unroll
      for (int dblk = 0; dblk < 4; dblk++) accO[g][dblk] = mfma16x32(pp0, vf[dblk], accO[g][dblk]);
#pragma unroll
      for (int dblk = 0; dblk < 4; dblk++) accO[g][dblk] = mfma16x32(pp1, vf[4 + dblk], accO[g][dblk]);
    }
  }

  // ---- FIX: reduce l across quads so lred holds the wave's FULL sum ----
#pragma unroll
  for (int g = 0; g < 4; g++) {
    l_acc[g] += __shfl_xor(l_acc[g], 16);
    l_acc[g] += __shfl_xor(l_acc[g], 32);
  }

  // ---- cross-wave merge (flash-decoding style) ----
  if (quad == 0) {
#pragma unroll
    for (int g = 0; g < 4; g++) {
      mred[g][wave][l15] = m_i[g];
      lred[g][wave][l15] = l_acc[g];
    }
  }
  __syncthreads();

  float alpha[4], linvG[4];
#pragma unroll
  for (int g = 0; g < 4; g++) {
    float a0 = mred[g][0][l15], a1 = mred[g][1][l15];
    float a2 = mred[g][2][l15], a3 = mred[g][3][l15];
    float ms = fmaxf(fmaxf(a0, a1), fmaxf(a2, a3));
    float ls = __builtin_amdgcn_exp2f(a0 - ms) * lred[g][0][l15]
             + __builtin_amdgcn_exp2f(a1 - ms) * lred[g][1][l15]
             + __builtin_amdgcn_exp2f(a2 - ms) * lred[g][2][l15]
             + __builtin_amdgcn_exp2f(a3 - ms) * lred[g][3][l15];
    alpha[g] = __builtin_amdgcn_exp2f(m_i[g] - ms);
    linvG[g] = 1.0f / ls;
  }
  // rescale own accO to the global max base
#pragma unroll
  for (int g = 0; g < 4; g++) {
    float arow[4];
#pragma unroll
    for (int r = 0; r < 4; r++) arow[r] = __shfl(alpha[g], quad * 4 + r);
#pragma unroll
    for (int d = 0; d < 4; d++)
#pragma unroll
      for (int r = 0; r < 4; r++) accO[g][d][r] *= arow[r];
  }
  // accumulate O across waves in obuf
#pragma unroll
  for (int w = 0; w < 4; w++) {
    if (wave == w) {
#pragma unroll
      for (int g = 0; g < 4; g++)
#pragma unroll
        for (int dblk = 0; dblk < 4; dblk++)
#pragma unroll
          for (int r = 0; r < 4; r++) {
            int idx = (g * 16 + quad * 4 + r) * 64 + dblk * 16 + l15;
            if (w == 0) obuf[idx] = accO[g][dblk][r];
            else        obuf[idx] += accO[g][dblk][r];
          }
    }
    __syncthreads();
  }
  // final: wave writes q-rows [wave*16, wave*16+16), normalized
  float lw = wave == 0 ? linvG[0] : wave == 1 ? linvG[1] : wave == 2 ? linvG[2] : linvG[3];
  float lrow[4];
#pragma unroll
  for (int r = 0; r < 4; r++) lrow[r] = __shfl(lw, quad * 4 + r);
#pragma unroll
  for (int dblk = 0; dblk < 4; dblk++) {
#pragma unroll
    for (int r = 0; r < 4; r++) {
      int ql = wave * 16 + quad * 4 + r;
      float val = obuf[ql * 64 + dblk * 16 + l15] * lrow[r];
      O[((size_t)(b * 2048 + qbase + ql) << 10) + h * 64 + dblk * 16 + l15] = (f16)val;
    }
  }
}

// ------------- GEMM2: out = Ow @ Wout_t^T (fp32 out), 128(M)x64(N) tiles -------------
__global__ __launch_bounds__(256, 2) void gemm_out_kernel(
    const f16* __restrict__ Oh, const f16* __restrict__ Wt, float* __restrict__ out) {
  __shared__ __align__(16) f16 As[128 * 32];  // [m][k]
  __shared__ __align__(16) f16 Bs[64 * 32];   // [n][k]

  int tid = threadIdx.x;
  int lane = tid & 63, wave = tid >> 6;
  int l15 = lane & 15, quad = lane >> 4;
  int rowl = lane >> 2;
  int col8 = (lane & 3) * 8;
  int m0 = blockIdx.y * 128, n0 = blockIdx.x * 64;
  int wr = wave * 32;

  f32x4 acc[2][4];
#pragma unroll
  for (int i = 0; i < 2; i++)
#pragma unroll
    for (int j = 0; j < 4; j++) acc[i][j] = f32x4{0.f, 0.f, 0.f, 0.f};

  for (int kt = 0; kt < 32; kt++) {
    int kk = kt * 32;
#pragma unroll
    for (int c = 0; c < 2; c++) {
      int row = wave * 32 + c * 16 + rowl;
      gload_lds16(Oh + (size_t)(m0 + row) * 1024 + kk + col8, &As[(wave * 32 + c * 16) * 32]);
    }
    {
      int row = wave * 16 + rowl;
      gload_lds16(Wt + (size_t)(n0 + row) * 1024 + kk + col8, &Bs[(wave * 16) * 32]);
    }
    __syncthreads();
    f16x8 af[2], bf[4];
#pragma unroll
    for (int i = 0; i < 2; i++) af[i] = *(const f16x8*)(&As[(wr + i * 16 + l15) * 32 + quad * 8]);
#pragma unroll
    for (int j = 0; j < 4; j++) bf[j] = *(const f16x8*)(&Bs[(j * 16 + l15) * 32 + quad * 8]);
#pragma unroll
    for (int i = 0; i < 2; i++)
#pragma unroll
      for (int j = 0; j < 4; j++) acc[i][j] = mfma16x32(af[i], bf[j], acc[i][j]);
    __syncthreads();
  }

#pragma unroll
  for (int i = 0; i < 2; i++) {
#pragma unroll
    for (int j = 0; j < 4; j++) {
      int n = n0 + j * 16 + l15;
#pragma unroll
      for (int r = 0; r < 4; r++) {
        int m = m0 + wr + i * 16 + quad * 4 + r;
        out[((size_t)m << 10) + n] = acc[i][j][r];
      }
    }
  }
}

extern "C" void kernel_launch(void* const* d_in, const int* in_sizes, int n_in,
                              void* d_out, int out_size, void* d_ws, size_t ws_size,
                              hipStream_t stream) {
  const float* X = (const float*)d_in[0];     // (2,2048,1024)
  const float* Wqkv = (const float*)d_in[1];  // (1024,3072)
  const float* Wout = (const float*)d_in[2];  // (1024,1024)
  const float* rel = (const float*)d_in[3];   // (32,16)

  char* ws = (char*)d_ws;
  f16* Xh     = (f16*)(ws + 0);
  f16* Wqkv_t = (f16*)(ws + 8388608);
  f16* Wout_t = (f16*)(ws + 14680064);
  f16* Qw     = (f16*)(ws + 16777216);
  f16* Kp     = (f16*)(ws + 25165824);
  f16* Vp     = (f16*)(ws + 33554432);
  f16* Ow     = (f16*)(ws + 41943040);
  float* btab = (float*)(ws + 50331648);

  prep_kernel<<<8208, 256, 0, stream>>>(X, Wqkv, Wout, rel, Xh, Wqkv_t, Wout_t, btab);
  gemm_qkv_kernel<<<dim3(24, 32), 256, 0, stream>>>(Xh, Wqkv_t, Qw, Kp, Vp);
  attn_kernel<<<1024, 256, 0, stream>>>(Qw, Kp, Vp, btab, Ow);
  gemm_out_kernel<<<dim3(16, 32), 256, 0, stream>>>(Ow, Wout_t, (float*)d_out);
}